// Round 5
// baseline (27.007 us; speedup 1.0000x reference)
//
#include <hip/hip_runtime.h>
#include <hip/hip_bf16.h>

// x:[8,160,160,64] f32, pos:[8,4096,2] f32, H=W=1280 (device int scalars).
// out:[8,4096,64] f32.
constexpr int B  = 8;
constexpr int Hf = 160;
constexpr int Wf = 160;
constexpr int C  = 64;
constexpr int N  = 4096;
constexpr int NXCD = 8;

// 2D tile binning: 13x13-pixel tiles -> 13x13 = 169 bins per batch.
constexpr int TILE = 13;
constexpr int TPS  = 13;               // tiles per side (160/13 -> 0..12)
constexpr int BINS = TPS * TPS;        // 169
constexpr int CAP  = 64;               // bucket capacity (avg 24.2, sigma ~5)
constexpr int OBLK = 64;               // overflow-scan blocks per batch
constexpr int CNTS = BINS + 1;         // per-batch counters (+1 = overflow count)

// ws layout (ints): [counters B*CNTS][buckets B*BINS*CAP][overflow B*N]
constexpr size_t WS_NEED = (size_t)(B * CNTS + B * BINS * CAP + B * N) * 4;

typedef float f32x4 __attribute__((ext_vector_type(4)));
typedef float f32x2 __attribute__((ext_vector_type(2)));

__device__ __forceinline__ void cubic_weights(float t, float w[4]) {
    const float A = -0.75f;
    float s;
    s = t + 1.0f;
    w[0] = ((A * s - 5.0f * A) * s + 8.0f * A) * s - 4.0f * A;
    s = t;
    w[1] = ((A + 2.0f) * s - (A + 3.0f)) * s * s + 1.0f;
    s = 1.0f - t;
    w[2] = ((A + 2.0f) * s - (A + 3.0f)) * s * s + 1.0f;
    s = 2.0f - t;
    w[3] = ((A * s - 5.0f * A) * s + 8.0f * A) * s - 4.0f * A;
}

// Shared per-point body: 16 lanes (q = channel quad) evaluate one point.
__device__ __forceinline__ void eval_point(const float* __restrict__ xb,  // batch base + q*4
                                           const float* __restrict__ pos,
                                           float* __restrict__ out,
                                           int pnt, int q, float Wo, float Ho) {
    f32x2 p = *reinterpret_cast<const f32x2*>(pos + (size_t)pnt * 2);

    float gx = 2.0f * p.x / (Wo - 1.0f) - 1.0f;
    float gy = 2.0f * p.y / (Ho - 1.0f) - 1.0f;
    float ix = ((gx + 1.0f) * (float)Wf - 1.0f) * 0.5f;
    float iy = ((gy + 1.0f) * (float)Hf - 1.0f) * 0.5f;

    float fx = floorf(ix), fy = floorf(iy);
    float tx = ix - fx,    ty = iy - fy;
    int x0 = (int)fx, y0 = (int)fy;

    float wx[4], wy[4];
    cubic_weights(tx, wx);
    cubic_weights(ty, wy);

    int yc[4], xc[4];
    #pragma unroll
    for (int i = 0; i < 4; ++i) {
        int yi = y0 - 1 + i;
        wy[i] = (yi >= 0 && yi < Hf) ? wy[i] : 0.0f;
        yc[i] = min(max(yi, 0), Hf - 1);
        int xj = x0 - 1 + i;
        wx[i] = (xj >= 0 && xj < Wf) ? wx[i] : 0.0f;
        xc[i] = min(max(xj, 0), Wf - 1);
    }

    f32x4 v[4][4];
    #pragma unroll
    for (int i = 0; i < 4; ++i) {
        const float* row = xb + (size_t)yc[i] * (Wf * C);
        #pragma unroll
        for (int j = 0; j < 4; ++j)
            v[i][j] = *reinterpret_cast<const f32x4*>(row + (size_t)xc[j] * C);
    }

    f32x4 acc = {0.f, 0.f, 0.f, 0.f};
    #pragma unroll
    for (int i = 0; i < 4; ++i) {
        #pragma unroll
        for (int j = 0; j < 4; ++j) {
            float w = wy[i] * wx[j];
            acc.x = fmaf(w, v[i][j].x, acc.x);
            acc.y = fmaf(w, v[i][j].y, acc.y);
            acc.z = fmaf(w, v[i][j].z, acc.z);
            acc.w = fmaf(w, v[i][j].w, acc.w);
        }
    }

    f32x4* op = reinterpret_cast<f32x4*>(out + (size_t)pnt * C + q * 4);
    __builtin_nontemporal_store(acc, op);
}

// Pre-pass: bin each point into its 13x13 pixel tile (atomic buckets in ws).
// Output values are independent of atomic ordering -> deterministic results.
__global__ __launch_bounds__(256)
void bin_points(const float* __restrict__ pos, const int* __restrict__ Hp,
                const int* __restrict__ Wp, int* __restrict__ ws) {
    int pid = blockIdx.x * blockDim.x + threadIdx.x;
    if (pid >= B * N) return;
    int b = pid / N, n = pid - b * N;

    f32x2 p = *reinterpret_cast<const f32x2*>(pos + (size_t)pid * 2);
    float Wo = (float)Wp[0], Ho = (float)Hp[0];
    float gx = 2.0f * p.x / (Wo - 1.0f) - 1.0f;
    float gy = 2.0f * p.y / (Ho - 1.0f) - 1.0f;
    float ix = ((gx + 1.0f) * (float)Wf - 1.0f) * 0.5f;
    float iy = ((gy + 1.0f) * (float)Hf - 1.0f) * 0.5f;
    int x0 = min(max((int)floorf(ix), 0), Wf - 1);
    int y0 = min(max((int)floorf(iy), 0), Hf - 1);
    int bin = (y0 / TILE) * TPS + (x0 / TILE);

    int* cnt    = ws;
    int* bucket = ws + B * CNTS;
    int* ovf    = bucket + B * BINS * CAP;

    int slot = atomicAdd(&cnt[b * CNTS + bin], 1);
    if (slot < CAP) {
        bucket[((size_t)b * BINS + bin) * CAP + slot] = n;
    } else {
        int os = atomicAdd(&cnt[b * CNTS + BINS], 1);
        ovf[b * N + os] = n;
    }
}

// Main: one block per (batch, bin); batch == blockIdx%8 -> XCD-affine.
// 256 threads = 16 points x 16 channel-quads; loop bin contents in chunks of 16.
__global__ __launch_bounds__(256)
void interp_binned(const float* __restrict__ x, const float* __restrict__ pos,
                   const int* __restrict__ Hp, const int* __restrict__ Wp,
                   const int* __restrict__ ws, float* __restrict__ out) {
    int g = blockIdx.x;
    int b = g & (NXCD - 1);
    int u = g >> 3;                      // 0 .. BINS+OBLK-1

    const int* cnt    = ws;
    const int* bucket = ws + B * CNTS;
    const int* ovf    = bucket + B * BINS * CAP;

    int q   = threadIdx.x & 15;
    int pib = threadIdx.x >> 4;
    float Wo = (float)Wp[0], Ho = (float)Hp[0];
    const float* xb = x + (size_t)b * (Hf * Wf * C) + q * 4;

    if (u < BINS) {
        int cv = cnt[b * CNTS + u];
        int m  = min(cv, CAP);
        const int* list = bucket + ((size_t)b * BINS + u) * CAP;
        for (int base = 0; base < m; base += 16) {
            int i = base + pib;
            if (i < m) {
                int n = list[i];
                eval_point(xb, pos, out, b * N + n, q, Wo, Ho);
            }
        }
    } else {
        // Overflow scan: OBLK blocks stripe over the (normally empty) list.
        int j  = u - BINS;
        int ov = cnt[b * CNTS + BINS];
        for (int base = j * 16; base < ov; base += OBLK * 16) {
            int i = base + pib;
            if (i < ov) {
                int n = ovf[b * N + i];
                eval_point(xb, pos, out, b * N + n, q, Wo, Ho);
            }
        }
    }
}

// Fallback (R3 kernel) if ws is too small for the binning structures.
__global__ __launch_bounds__(256)
void interp_direct(const float* __restrict__ x, const float* __restrict__ pos,
                   const int* __restrict__ Hp, const int* __restrict__ Wp,
                   float* __restrict__ out) {
    int blk  = blockIdx.x;
    int b    = blk & (NXCD - 1);
    int slot = blk >> 3;
    int q    = threadIdx.x & 15;
    int pib  = threadIdx.x >> 4;
    int pnt  = b * N + slot * 16 + pib;
    float Wo = (float)Wp[0], Ho = (float)Hp[0];
    const float* xb = x + (size_t)b * (Hf * Wf * C) + q * 4;
    eval_point(xb, pos, out, pnt, q, Wo, Ho);
}

extern "C" void kernel_launch(void* const* d_in, const int* in_sizes, int n_in,
                              void* d_out, int out_size, void* d_ws, size_t ws_size,
                              hipStream_t stream) {
    const float* x   = (const float*)d_in[0];
    const float* pos = (const float*)d_in[1];
    const int*   Hp  = (const int*)d_in[2];
    const int*   Wp  = (const int*)d_in[3];
    float* out = (float*)d_out;

    if (ws_size < WS_NEED) {
        int grid = B * (N / 16);
        interp_direct<<<grid, 256, 0, stream>>>(x, pos, Hp, Wp, out);
        return;
    }

    int* ws = (int*)d_ws;
    // Zero only the counters (5.4 KB). Async memset is graph-capture safe.
    hipMemsetAsync(ws, 0, (size_t)B * CNTS * sizeof(int), stream);

    bin_points<<<(B * N + 255) / 256, 256, 0, stream>>>(pos, Hp, Wp, ws);

    int grid = B * (BINS + OBLK);   // 1864 blocks
    interp_binned<<<grid, 256, 0, stream>>>(x, pos, Hp, Wp, ws, out);
}

// Round 6
// 23.860 us; speedup vs baseline: 1.1319x; 1.1319x over previous
//
#include <hip/hip_runtime.h>
#include <hip/hip_bf16.h>

// x:[8,160,160,64] f32, pos:[8,4096,2] f32, H=W=1280 (device int scalars).
// out:[8,4096,64] f32.
constexpr int B  = 8;
constexpr int Hf = 160;
constexpr int Wf = 160;
constexpr int C  = 64;
constexpr int N  = 4096;
constexpr int NXCD = 8;

// bf16 copy of x in d_ws: per-batch 160*160*64*2 = 3.28 MB  (< 4 MB L2/XCD).
constexpr size_t WS_NEED = (size_t)B * Hf * Wf * C * 2;   // 26.2 MB

typedef float    f32x4  __attribute__((ext_vector_type(4)));
typedef float    f32x2  __attribute__((ext_vector_type(2)));
typedef unsigned short u16x8 __attribute__((ext_vector_type(8)));
typedef unsigned int   u32x2 __attribute__((ext_vector_type(2)));

__device__ __forceinline__ unsigned short f2bf_rne(float f) {
    unsigned int u = __builtin_bit_cast(unsigned int, f);
    u = (u + 0x7fffu + ((u >> 16) & 1u)) >> 16;       // round-to-nearest-even
    return (unsigned short)u;
}
__device__ __forceinline__ float bf_lo(unsigned int w) {   // low bf16 -> f32
    return __builtin_bit_cast(float, w << 16);
}
__device__ __forceinline__ float bf_hi(unsigned int w) {   // high bf16 -> f32
    return __builtin_bit_cast(float, w & 0xffff0000u);
}

__device__ __forceinline__ void cubic_weights(float t, float w[4]) {
    const float A = -0.75f;
    float s;
    s = t + 1.0f;
    w[0] = ((A * s - 5.0f * A) * s + 8.0f * A) * s - 4.0f * A;
    s = t;
    w[1] = ((A + 2.0f) * s - (A + 3.0f)) * s * s + 1.0f;
    s = 1.0f - t;
    w[2] = ((A + 2.0f) * s - (A + 3.0f)) * s * s + 1.0f;
    s = 2.0f - t;
    w[3] = ((A * s - 5.0f * A) * s + 8.0f * A) * s - 4.0f * A;
}

// ---------- pass 1: f32 -> bf16, XCD-affine (batch b on XCD b) ----------
// Grid = B * 800 blocks; 256 threads x 8 elems = 2048 elems/block.
// Writes are NOT nontemporal: we WANT the 3.28 MB/batch dirty in that XCD's L2.
__global__ __launch_bounds__(256)
void convert_bf16(const float* __restrict__ x, unsigned short* __restrict__ xh) {
    int blk  = blockIdx.x;
    int b    = blk & (NXCD - 1);
    int slot = blk >> 3;                               // 0..799
    size_t base = (size_t)b * (Hf * Wf * C)
                + (size_t)slot * (256 * 8) + (size_t)threadIdx.x * 8;
    const f32x4* src = reinterpret_cast<const f32x4*>(x + base);
    f32x4 a = src[0], c = src[1];
    u16x8 o;
    o[0] = f2bf_rne(a.x); o[1] = f2bf_rne(a.y);
    o[2] = f2bf_rne(a.z); o[3] = f2bf_rne(a.w);
    o[4] = f2bf_rne(c.x); o[5] = f2bf_rne(c.y);
    o[6] = f2bf_rne(c.z); o[7] = f2bf_rne(c.w);
    *reinterpret_cast<u16x8*>(xh + base) = o;
}

// ---------- pass 2: bicubic gather from bf16 (L2-resident per XCD) ----------
// 16 lanes per point, lane q owns channels [4q,4q+4): one 8 B load per tap,
// so a point's tap = 128 B = exactly one cache line.
__global__ __launch_bounds__(256)
void interp_bf16(const unsigned short* __restrict__ xh,
                 const float* __restrict__ pos,
                 const int* __restrict__ Hp, const int* __restrict__ Wp,
                 float* __restrict__ out) {
    int blk  = blockIdx.x;
    int b    = blk & (NXCD - 1);          // batch == XCD slot
    int slot = blk >> 3;
    int q    = threadIdx.x & 15;
    int pib  = threadIdx.x >> 4;
    int pnt  = b * N + slot * 16 + pib;

    f32x2 p = *reinterpret_cast<const f32x2*>(pos + (size_t)pnt * 2);
    float Wo = (float)Wp[0], Ho = (float)Hp[0];

    float gx = 2.0f * p.x / (Wo - 1.0f) - 1.0f;
    float gy = 2.0f * p.y / (Ho - 1.0f) - 1.0f;
    float ix = ((gx + 1.0f) * (float)Wf - 1.0f) * 0.5f;
    float iy = ((gy + 1.0f) * (float)Hf - 1.0f) * 0.5f;

    float fx = floorf(ix), fy = floorf(iy);
    float tx = ix - fx,    ty = iy - fy;
    int x0 = (int)fx, y0 = (int)fy;

    float wx[4], wy[4];
    cubic_weights(tx, wx);
    cubic_weights(ty, wy);

    int yc[4], xc[4];
    #pragma unroll
    for (int i = 0; i < 4; ++i) {
        int yi = y0 - 1 + i;
        wy[i] = (yi >= 0 && yi < Hf) ? wy[i] : 0.0f;
        yc[i] = min(max(yi, 0), Hf - 1);
        int xj = x0 - 1 + i;
        wx[i] = (xj >= 0 && xj < Wf) ? wx[i] : 0.0f;
        xc[i] = min(max(xj, 0), Wf - 1);
    }

    const unsigned short* xb = xh + (size_t)b * (Hf * Wf * C) + q * 4;

    // Issue all 16 8-byte loads, then unpack + reduce.
    u32x2 v[4][4];
    #pragma unroll
    for (int i = 0; i < 4; ++i) {
        const unsigned short* row = xb + (size_t)yc[i] * (Wf * C);
        #pragma unroll
        for (int j = 0; j < 4; ++j)
            v[i][j] = *reinterpret_cast<const u32x2*>(row + (size_t)xc[j] * C);
    }

    float a0 = 0.f, a1 = 0.f, a2 = 0.f, a3 = 0.f;
    #pragma unroll
    for (int i = 0; i < 4; ++i) {
        #pragma unroll
        for (int j = 0; j < 4; ++j) {
            float w = wy[i] * wx[j];
            unsigned int lo = v[i][j].x, hi = v[i][j].y;
            a0 = fmaf(w, bf_lo(lo), a0);
            a1 = fmaf(w, bf_hi(lo), a1);
            a2 = fmaf(w, bf_lo(hi), a2);
            a3 = fmaf(w, bf_hi(hi), a3);
        }
    }

    f32x4 acc = {a0, a1, a2, a3};
    f32x4* op = reinterpret_cast<f32x4*>(out + (size_t)pnt * C + q * 4);
    __builtin_nontemporal_store(acc, op);
}

// ---------- fallback: R4 direct f32 kernel (if ws too small) ----------
__global__ __launch_bounds__(256)
void interp_direct(const float* __restrict__ x, const float* __restrict__ pos,
                   const int* __restrict__ Hp, const int* __restrict__ Wp,
                   float* __restrict__ out) {
    int blk  = blockIdx.x;
    int b    = blk & (NXCD - 1);
    int slot = blk >> 3;
    int q    = threadIdx.x & 15;
    int pib  = threadIdx.x >> 4;
    int pnt  = b * N + slot * 16 + pib;

    f32x2 p = *reinterpret_cast<const f32x2*>(pos + (size_t)pnt * 2);
    float Wo = (float)Wp[0], Ho = (float)Hp[0];

    float gx = 2.0f * p.x / (Wo - 1.0f) - 1.0f;
    float gy = 2.0f * p.y / (Ho - 1.0f) - 1.0f;
    float ix = ((gx + 1.0f) * (float)Wf - 1.0f) * 0.5f;
    float iy = ((gy + 1.0f) * (float)Hf - 1.0f) * 0.5f;

    float fx = floorf(ix), fy = floorf(iy);
    float tx = ix - fx,    ty = iy - fy;
    int x0 = (int)fx, y0 = (int)fy;

    float wx[4], wy[4];
    cubic_weights(tx, wx);
    cubic_weights(ty, wy);

    int yc[4], xc[4];
    #pragma unroll
    for (int i = 0; i < 4; ++i) {
        int yi = y0 - 1 + i;
        wy[i] = (yi >= 0 && yi < Hf) ? wy[i] : 0.0f;
        yc[i] = min(max(yi, 0), Hf - 1);
        int xj = x0 - 1 + i;
        wx[i] = (xj >= 0 && xj < Wf) ? wx[i] : 0.0f;
        xc[i] = min(max(xj, 0), Wf - 1);
    }

    const float* xb = x + (size_t)b * (Hf * Wf * C) + q * 4;
    f32x4 v[4][4];
    #pragma unroll
    for (int i = 0; i < 4; ++i) {
        const float* row = xb + (size_t)yc[i] * (Wf * C);
        #pragma unroll
        for (int j = 0; j < 4; ++j)
            v[i][j] = *reinterpret_cast<const f32x4*>(row + (size_t)xc[j] * C);
    }
    f32x4 acc = {0.f, 0.f, 0.f, 0.f};
    #pragma unroll
    for (int i = 0; i < 4; ++i) {
        #pragma unroll
        for (int j = 0; j < 4; ++j) {
            float w = wy[i] * wx[j];
            acc.x = fmaf(w, v[i][j].x, acc.x);
            acc.y = fmaf(w, v[i][j].y, acc.y);
            acc.z = fmaf(w, v[i][j].z, acc.z);
            acc.w = fmaf(w, v[i][j].w, acc.w);
        }
    }
    f32x4* op = reinterpret_cast<f32x4*>(out + (size_t)pnt * C + q * 4);
    __builtin_nontemporal_store(acc, op);
}

extern "C" void kernel_launch(void* const* d_in, const int* in_sizes, int n_in,
                              void* d_out, int out_size, void* d_ws, size_t ws_size,
                              hipStream_t stream) {
    const float* x   = (const float*)d_in[0];
    const float* pos = (const float*)d_in[1];
    const int*   Hp  = (const int*)d_in[2];
    const int*   Wp  = (const int*)d_in[3];
    float* out = (float*)d_out;

    if (ws_size < WS_NEED) {
        interp_direct<<<B * (N / 16), 256, 0, stream>>>(x, pos, Hp, Wp, out);
        return;
    }

    unsigned short* xh = (unsigned short*)d_ws;
    // 8 batches x 800 blocks; batch b on XCD b so its bf16 map lands in that L2.
    convert_bf16<<<B * (Hf * Wf * C / (256 * 8)), 256, 0, stream>>>(x, xh);
    interp_bf16<<<B * (N / 16), 256, 0, stream>>>(xh, pos, Hp, Wp, out);
}

// Round 7
// 14.937 us; speedup vs baseline: 1.8080x; 1.5973x over previous
//
#include <hip/hip_runtime.h>
#include <hip/hip_bf16.h>

// x:[8,160,160,64] f32, pos:[8,4096,2] f32, H=W=1280 (device int scalars).
// out:[8,4096,64] f32.
constexpr int B  = 8;
constexpr int Hf = 160;
constexpr int Wf = 160;
constexpr int C  = 64;
constexpr int N  = 4096;

typedef float f32x4 __attribute__((ext_vector_type(4)));
typedef float f32x2 __attribute__((ext_vector_type(2)));

__device__ __forceinline__ void cubic_weights(float t, float w[4]) {
    const float A = -0.75f;
    float s;
    s = t + 1.0f;
    w[0] = ((A * s - 5.0f * A) * s + 8.0f * A) * s - 4.0f * A;
    s = t;
    w[1] = ((A + 2.0f) * s - (A + 3.0f)) * s * s + 1.0f;
    s = 1.0f - t;
    w[2] = ((A + 2.0f) * s - (A + 3.0f)) * s * s + 1.0f;
    s = 2.0f - t;
    w[3] = ((A * s - 5.0f * A) * s + 8.0f * A) * s - 4.0f * A;
}

// XCD-sliced gather: XCD slot s = blockIdx%8 owns (batch pair s>>1, channel
// half s&1). Slice footprint = 160*160*32ch*4B * 2 batches = 3.28 MB < 4 MB
// L2/XCD -> taps are ~all L2 hits in steady state (slices persist across
// graph replays; output uses nontemporal stores to avoid evicting them).
// 8 lanes per (point, half): one tap load = 8 lanes x 16 B = one 128 B line.
// Block = 256 threads = 32 points x 8 lanes. Grid = 2048 blocks.
__global__ __launch_bounds__(256)
void interp_sliced(const float* __restrict__ x, const float* __restrict__ pos,
                   const int* __restrict__ Hp, const int* __restrict__ Wp,
                   float* __restrict__ out) {
    int g    = blockIdx.x;
    int s    = g & 7;               // XCD slot
    int pair = s >> 1;              // batch pair 0..3
    int h    = s & 1;               // channel half 0..1
    int slot = g >> 3;              // 0..255
    int q    = threadIdx.x & 7;     // channel quad within half
    int pib  = threadIdx.x >> 3;    // point-in-block 0..31
    int pp   = slot * 32 + pib;     // point within pair 0..8191
    int b    = pair * 2 + (pp >> 12);
    int n    = pp & (N - 1);
    int pnt  = b * N + n;

    f32x2 p = *reinterpret_cast<const f32x2*>(pos + (size_t)pnt * 2);
    float Wo = (float)Wp[0], Ho = (float)Hp[0];

    // Match reference math exactly (align_corners=False chain).
    float gx = 2.0f * p.x / (Wo - 1.0f) - 1.0f;
    float gy = 2.0f * p.y / (Ho - 1.0f) - 1.0f;
    float ix = ((gx + 1.0f) * (float)Wf - 1.0f) * 0.5f;
    float iy = ((gy + 1.0f) * (float)Hf - 1.0f) * 0.5f;

    float fx = floorf(ix), fy = floorf(iy);
    float tx = ix - fx,    ty = iy - fy;
    int x0 = (int)fx, y0 = (int)fy;

    float wx[4], wy[4];
    cubic_weights(tx, wx);
    cubic_weights(ty, wy);

    // Branchless zeros-padding: clamp index, zero weight (== reference clip+mask).
    int yc[4], xc[4];
    #pragma unroll
    for (int i = 0; i < 4; ++i) {
        int yi = y0 - 1 + i;
        wy[i] = (yi >= 0 && yi < Hf) ? wy[i] : 0.0f;
        yc[i] = min(max(yi, 0), Hf - 1);
        int xj = x0 - 1 + i;
        wx[i] = (xj >= 0 && xj < Wf) ? wx[i] : 0.0f;
        xc[i] = min(max(xj, 0), Wf - 1);
    }

    int ch = h * 32 + q * 4;        // this lane's channel base
    const float* xb = x + (size_t)b * (Hf * Wf * C) + ch;

    // Issue all 16 independent tap loads, then reduce.
    f32x4 v[4][4];
    #pragma unroll
    for (int i = 0; i < 4; ++i) {
        const float* row = xb + (size_t)yc[i] * (Wf * C);
        #pragma unroll
        for (int j = 0; j < 4; ++j)
            v[i][j] = *reinterpret_cast<const f32x4*>(row + (size_t)xc[j] * C);
    }

    f32x4 acc = {0.f, 0.f, 0.f, 0.f};
    #pragma unroll
    for (int i = 0; i < 4; ++i) {
        #pragma unroll
        for (int j = 0; j < 4; ++j) {
            float w = wy[i] * wx[j];
            acc.x = fmaf(w, v[i][j].x, acc.x);
            acc.y = fmaf(w, v[i][j].y, acc.y);
            acc.z = fmaf(w, v[i][j].z, acc.z);
            acc.w = fmaf(w, v[i][j].w, acc.w);
        }
    }

    // Nontemporal: keep the 8.4 MB output stream from evicting the L2 slices.
    f32x4* op = reinterpret_cast<f32x4*>(out + (size_t)pnt * C + ch);
    __builtin_nontemporal_store(acc, op);
}

extern "C" void kernel_launch(void* const* d_in, const int* in_sizes, int n_in,
                              void* d_out, int out_size, void* d_ws, size_t ws_size,
                              hipStream_t stream) {
    const float* x   = (const float*)d_in[0];
    const float* pos = (const float*)d_in[1];
    const int*   Hp  = (const int*)d_in[2];
    const int*   Wp  = (const int*)d_in[3];
    float* out = (float*)d_out;

    // 4 batch-pairs x 2 channel-halves x 256 point-slots = 2048 blocks.
    interp_sliced<<<2048, 256, 0, stream>>>(x, pos, Hp, Wp, out);
}